// Round 1
// baseline (426.441 us; speedup 1.0000x reference)
//
#include <hip/hip_runtime.h>

#define NUM_CARDS 50000
#define NM1 49999
#define EMBED_DIM 64
#define HIDDEN 256
#define BATCH 1024
#define NTILES 3125            // 3125*16 = 50000 = NM1 + 1 pad column
#define LOGEPS -16.118095651f  // ln(1e-7)
#define KLEPS 1e-7f

typedef __attribute__((ext_vector_type(8))) short short8;  // 8 bf16 in 4 VGPRs
typedef __attribute__((ext_vector_type(4))) float f32x4;

// ws layout (total 6,535,184 B):
//   A bf16   : [0,       131072)   1024*64*2
//   B bf16   : [131072,  6531072)  50000*64*2 (row j = normalized card j+1; row 49999 = 0)
//   sumexp   : [6531072, 6535168)  1024*4
//   acc      : [6535168, 6535172)
#define A_OFF   0
#define B_OFF   131072
#define SUM_OFF 6531072
#define ACC_OFF 6535168

__device__ inline unsigned short f2bf(float x) {
    unsigned int u = __float_as_uint(x);
    return (unsigned short)((u + 0x7FFFu + ((u >> 16) & 1u)) >> 16);  // RNE
}

// ---------------- MLP: emb -> relu(emb@W1+b1) -> @W2+b2 -> l2norm -> bf16 A ----------------
__global__ __launch_bounds__(256) void mlp_kernel(
    const int* __restrict__ idx, const float* __restrict__ ce,
    const float* __restrict__ W1, const float* __restrict__ b1,
    const float* __restrict__ W2, const float* __restrict__ b2,
    unsigned short* __restrict__ Abf)
{
    __shared__ float emb_s[8][64];
    __shared__ float hs[8][256];
    __shared__ int idx_s[8];
    const int t = threadIdx.x;
    const int i0 = blockIdx.x * 8;
    if (t < 8) idx_s[t] = idx[i0 + t];
    __syncthreads();
    for (int e = t; e < 8 * 64; e += 256) {
        int g = e >> 6, k = e & 63;
        emb_s[g][k] = ce[idx_s[g] * 64 + k];
    }
    __syncthreads();
    {   // hidden layer: thread j computes h[g][j] for all 8 g
        const int j = t;
        float acc[8];
        float bj = b1[j];
        #pragma unroll
        for (int g = 0; g < 8; ++g) acc[g] = bj;
        for (int k = 0; k < 64; ++k) {
            float w = W1[k * 256 + j];
            #pragma unroll
            for (int g = 0; g < 8; ++g) acc[g] = fmaf(emb_s[g][k], w, acc[g]);
        }
        #pragma unroll
        for (int g = 0; g < 8; ++g) hs[g][j] = fmaxf(acc[g], 0.f);
    }
    __syncthreads();
    {   // output layer: wave wv handles rows wv and wv+4, lane = dim d
        const int d  = t & 63;
        const int wv = t >> 6;
        float o0 = b2[d], o1 = b2[d];
        for (int j = 0; j < 256; ++j) {
            float w2 = W2[j * 64 + d];
            o0 = fmaf(hs[wv][j],     w2, o0);
            o1 = fmaf(hs[wv + 4][j], w2, o1);
        }
        float s0 = o0 * o0, s1 = o1 * o1;
        #pragma unroll
        for (int m = 1; m <= 32; m <<= 1) {
            s0 += __shfl_xor(s0, m, 64);
            s1 += __shfl_xor(s1, m, 64);
        }
        o0 *= rsqrtf(fmaxf(s0, 1e-12f));
        o1 *= rsqrtf(fmaxf(s1, 1e-12f));
        Abf[(i0 + wv) * 64 + d]     = f2bf(o0);
        Abf[(i0 + wv + 4) * 64 + d] = f2bf(o1);
    }
}

// ---------------- Normalize card_embeddings[1:] -> bf16 B (row j = card j+1) ----------------
__global__ __launch_bounds__(256) void prep_b_kernel(
    const float* __restrict__ ce, unsigned short* __restrict__ Bbf)
{
    const int lane = threadIdx.x & 63;
    const int wv   = threadIdx.x >> 6;
    const int j    = blockIdx.x * 4 + wv;
    if (j >= NUM_CARDS) return;
    float v = (j < NM1) ? ce[(size_t)(j + 1) * 64 + lane] : 0.f;
    float ss = v * v;
    #pragma unroll
    for (int m = 1; m <= 32; m <<= 1) ss += __shfl_xor(ss, m, 64);
    float inv = rsqrtf(fmaxf(ss, 1e-12f));
    Bbf[(size_t)j * 64 + lane] = f2bf((j < NM1) ? v * inv : 0.f);
}

// ---------------- Pass 1: sumexp per row ----------------
__global__ __launch_bounds__(256) void pass1_kernel(
    const unsigned short* __restrict__ Abf,
    const unsigned short* __restrict__ Bbf,
    const float* __restrict__ temp_p,
    float* __restrict__ sumexp)
{
    const int lane = threadIdx.x & 63;
    const int wv   = threadIdx.x >> 6;
    const int n    = lane & 15;
    const int quad = lane >> 4;
    const int r0   = blockIdx.x * 64 + wv * 16;  // this wave's 16-row tile
    const float T  = *temp_p;

    const short8 a0 = *(const short8*)(Abf + (size_t)(r0 + n) * 64 + quad * 8);
    const short8 a1 = *(const short8*)(Abf + (size_t)(r0 + n) * 64 + 32 + quad * 8);

    float rs[4] = {0.f, 0.f, 0.f, 0.f};
    for (int ct = blockIdx.y; ct < NTILES; ct += gridDim.y) {
        const unsigned short* bp = Bbf + (size_t)(ct * 16 + n) * 64;
        const short8 b0 = *(const short8*)(bp + quad * 8);
        const short8 b1 = *(const short8*)(bp + 32 + quad * 8);
        f32x4 d = {0.f, 0.f, 0.f, 0.f};
        d = __builtin_amdgcn_mfma_f32_16x16x32_bf16(a0, b0, d, 0, 0, 0);
        d = __builtin_amdgcn_mfma_f32_16x16x32_bf16(a1, b1, d, 0, 0, 0);
        if (ct * 16 + n < NM1) {  // mask the single pad column
            #pragma unroll
            for (int r = 0; r < 4; ++r) rs[r] += __expf(T * d[r]);
        }
    }
    #pragma unroll
    for (int r = 0; r < 4; ++r) {
        float v = rs[r];
        v += __shfl_xor(v, 1, 64);
        v += __shfl_xor(v, 2, 64);
        v += __shfl_xor(v, 4, 64);
        v += __shfl_xor(v, 8, 64);
        if (n == 0) atomicAdd(&sumexp[r0 + quad * 4 + r], v);
    }
}

// ---------------- Pass 2: KL accumulation ----------------
__global__ __launch_bounds__(256) void pass2_kernel(
    const unsigned short* __restrict__ Abf,
    const unsigned short* __restrict__ Bbf,
    const float* __restrict__ adj,
    const float* __restrict__ temp_p,
    const float* __restrict__ sumexp,
    float* __restrict__ acc)
{
    const int lane = threadIdx.x & 63;
    const int wv   = threadIdx.x >> 6;
    const int n    = lane & 15;
    const int quad = lane >> 4;
    const int r0   = blockIdx.x * 64 + wv * 16;
    const float T  = *temp_p;

    const short8 a0 = *(const short8*)(Abf + (size_t)(r0 + n) * 64 + quad * 8);
    const short8 a1 = *(const short8*)(Abf + (size_t)(r0 + n) * 64 + 32 + quad * 8);

    float lse[4];
    const float* adjr[4];
    #pragma unroll
    for (int r = 0; r < 4; ++r) {
        int row = r0 + quad * 4 + r;
        lse[r]  = __logf(sumexp[row]);
        adjr[r] = adj + (size_t)row * NM1;
    }

    float local = 0.f;
    for (int ct = blockIdx.y; ct < NTILES; ct += gridDim.y) {
        const int j = ct * 16 + n;
        const unsigned short* bp = Bbf + (size_t)j * 64;
        const short8 b0 = *(const short8*)(bp + quad * 8);
        const short8 b1 = *(const short8*)(bp + 32 + quad * 8);
        f32x4 d = {0.f, 0.f, 0.f, 0.f};
        d = __builtin_amdgcn_mfma_f32_16x16x32_bf16(a0, b0, d, 0, 0, 0);
        d = __builtin_amdgcn_mfma_f32_16x16x32_bf16(a1, b1, d, 0, 0, 0);
        if (j < NM1) {
            #pragma unroll
            for (int r = 0; r < 4; ++r) {
                float yt = fmaxf(adjr[r][j], KLEPS);
                float lp = fmaxf(T * d[r] - lse[r], LOGEPS);  // log(clip(pred))
                local += yt * (__logf(yt) - lp);
            }
        }
    }
    #pragma unroll
    for (int m = 1; m <= 32; m <<= 1) local += __shfl_xor(local, m, 64);
    __shared__ float wacc[4];
    if (lane == 0) wacc[wv] = local;
    __syncthreads();
    if (threadIdx.x == 0) atomicAdd(acc, wacc[0] + wacc[1] + wacc[2] + wacc[3]);
}

// ---------------- Finalize ----------------
__global__ void fin_kernel(const float* __restrict__ acc,
                           const float* __restrict__ temp_p,
                           float* __restrict__ out)
{
    const float T = *temp_p;
    out[0] = acc[0] * (1.0f / (BATCH * 0.69314718055994531f)) + T * T * 0.01f;
}

extern "C" void kernel_launch(void* const* d_in, const int* in_sizes, int n_in,
                              void* d_out, int out_size, void* d_ws, size_t ws_size,
                              hipStream_t stream) {
    const int*   single_card = (const int*)d_in[0];
    const float* adj         = (const float*)d_in[1];
    const float* ce          = (const float*)d_in[2];
    const float* W1          = (const float*)d_in[3];
    const float* b1          = (const float*)d_in[4];
    const float* W2          = (const float*)d_in[5];
    const float* b2          = (const float*)d_in[6];
    const float* temp        = (const float*)d_in[7];

    char* ws = (char*)d_ws;
    unsigned short* Abf = (unsigned short*)(ws + A_OFF);
    unsigned short* Bbf = (unsigned short*)(ws + B_OFF);
    float* sumexp       = (float*)(ws + SUM_OFF);
    float* acc          = (float*)(ws + ACC_OFF);

    hipMemsetAsync(ws + SUM_OFF, 0, 4096 + 16, stream);  // sumexp + acc

    mlp_kernel<<<BATCH / 8, 256, 0, stream>>>(single_card, ce, W1, b1, W2, b2, Abf);
    prep_b_kernel<<<NUM_CARDS / 4, 256, 0, stream>>>(ce, Bbf);
    pass1_kernel<<<dim3(16, 128), 256, 0, stream>>>(Abf, Bbf, temp, sumexp);
    pass2_kernel<<<dim3(16, 128), 256, 0, stream>>>(Abf, Bbf, adj, temp, sumexp, acc);
    fin_kernel<<<1, 1, 0, stream>>>(acc, temp, (float*)d_out);
}